// Round 12
// baseline (128.590 us; speedup 1.0000x reference)
//
#include <hip/hip_runtime.h>
#include <math.h>

// Problem constants (from reference setup_inputs)
#define BB 32
#define TT 750
#define DD 2048
#define CC 20
#define MM 750
#define SS 64
#define MT 64          // gcn m-tile
#define NT 12          // tiles per batch
#define NPAIR 6        // tile pairs per batch
#define FSPLIT 16      // feat t-subchunks per (tz,fb); 47 rows each
#define FROWS 47
#define FUNITS (2 * BB * FSPLIT)   // 1024 feat units

#define GCNP_BLOCKS (NPAIR * BB)   // 192 gcn pair-blocks
#define TOT_BLOCKS (GCNP_BLOCKS + FUNITS + 1)  // 1217 = 19*64 + 1

#define ALPHA_W 0.0005f
#define BETA_W 0.1f
#define MARGIN_W 100.0f
#define GCN_W 0.1f
#define EPS_V 1e-8f

// ws float offsets
#define WS_LOSS01 0
#define WS_N2ACT 16
#define WS_N2BKG 48
#define WS_GCNB 80
#define WS_S2 128          // 2048 floats
#define WS_CAND 4096       // 32*64*12*8 = 196608 floats
#define WS_COLSUM 200704   // 2*32*16*2048 = 2097152 floats (ws ~9.2 MB)

typedef __attribute__((ext_vector_type(8))) short bf16x8;
typedef __attribute__((ext_vector_type(4))) float f32x4;

// f32 -> bf16 round-to-nearest-even
__device__ __forceinline__ unsigned short f2bf(float f) {
  unsigned int u = __float_as_uint(f);
  return (unsigned short)((u + 0x7FFFu + ((u >> 16) & 1u)) >> 16);
}

// ---------------------------------------------------------------------------
// Fused mega kernel, 512-thread blocks. 1216 = 19*64: bx%19 in {0,1,2} ->
// gcn pair-block (192), {3..18} -> feat unit (1024); bx==1216 -> bce.
// LEDGER (do not re-try):
//  - (256,6) launch bound: VGPR capped 40 -> gcn spilled; 208us.
//  - feat d-half split (strided spans): HBM fell to 1.78 TB/s.
//  - per-wave MLP levers (ILP-4/8, pipeline+sched_barrier, stealing, grid
//    x1.57 at 256thr/17.9KB-LDS): ALL null, HBM pinned 1.9-2.0 TB/s.
//  - PROVEN (R11): 512-thread zero-LDS feat blocks (32 waves/CU) stream at
//    ~4.5 TB/s; harness fillBuffer hits 7 TB/s (chip not the cap).
//  THIS ROUND: re-fuse at 512 threads; gcn = tile-pair blocks (shared A tile,
//  LDS 25.6KB -> 4 blocks/CU = 32 waves/CU cap preserved).
// ---------------------------------------------------------------------------
__global__ __launch_bounds__(512, 4) void mega_kernel(
    const float* __restrict__ score_act, const float* __restrict__ score_bkg,
    const float* __restrict__ feat_act, const float* __restrict__ feat_bkg,
    const float* __restrict__ label, const float* __restrict__ nodes,
    const int* __restrict__ nlab, const int* __restrict__ sidx,
    float* __restrict__ ws) {
  int bx = blockIdx.x;
  int tid = threadIdx.x;
  int q19 = bx / 19, r19 = bx % 19;

  if (bx < TOT_BLOCKS - 1 && r19 < 3) {
    // ------- GCN pair-block: batch b, tiles 2*pair, 2*pair+1 (bf16 MFMA) -----
    int idx = q19 * 3 + r19;         // 0..191
    int b = idx / NPAIR, pair = idx % NPAIR;
    int tileBase = pair * 2;

    __shared__ __align__(16) unsigned short sAh[64 * 64];      // 8 KB
    __shared__ __align__(16) unsigned short sBh[2][64 * 64];   // 16 KB
    __shared__ float sS2[SS];
    __shared__ float sN2[2][MT];
    __shared__ int sSlab[SS];
    __shared__ int sMlab[2][MT];

    if (tid < SS) {
      sSlab[tid] = nlab[b * MM + sidx[b * SS + tid]];
    } else if (tid < SS + 2 * MT) {
      int q = tid - SS;
      int grp = q >> 6, ml = q & 63;
      int m = (tileBase + grp) * MT + ml;
      sMlab[grp][ml] = (m < MM) ? nlab[b * MM + m] : -2;
    }

    // staging: thread -> row r = tid>>3 (A, B0, B1 rows), p = tid&7,
    // 8B-granules u = p+8j (j=0..1) of the 64-f32 chunk row.
    int r = tid >> 3, p = tid & 7;
    const float* aRow = nodes + ((size_t)b * MM + sidx[b * SS + r]) * DD;
    int m0row = tileBase * MT + r;   // tileBase <= 10 -> always < 750
    const float* b0Row = nodes + ((size_t)b * MM + m0row) * DD;
    int m1row = (tileBase + 1) * MT + r;
    bool b1val = (m1row < MM);
    const float* b1Row = nodes + ((size_t)b * MM + (b1val ? m1row : 0)) * DD;

    int wslot[2];  // ushort index of the 8B granule in the swizzled row
#pragma unroll
    for (int j = 0; j < 2; ++j) {
      int u = p + 8 * j;
      wslot[j] = r * 64 + ((((u >> 1) ^ (r & 7)) << 1) + (u & 1)) * 4;
    }

    int lane = tid & 63, w = tid >> 6;      // w = 0..7
    int grp = w >> 2, w4 = w & 3;           // grp: which tile of the pair
    int g = lane >> 4, c = lane & 15;

    float aSq = 0.f, b0Sq = 0.f, b1Sq = 0.f;
    f32x4 acc[4];
#pragma unroll
    for (int f = 0; f < 4; ++f) acc[f] = (f32x4){0.f, 0.f, 0.f, 0.f};

    // prefetch chunk 0
    float4 pa[2], pb0[2], pb1[2];
#pragma unroll
    for (int j = 0; j < 2; ++j) {
      int off = (p + 8 * j) * 4;
      pa[j] = *(const float4*)(aRow + off);
      pb0[j] = *(const float4*)(b0Row + off);
      pb1[j] = b1val ? *(const float4*)(b1Row + off)
                     : make_float4(0.f, 0.f, 0.f, 0.f);
    }

    for (int ch = 0; ch < 32; ++ch) {
      __syncthreads();  // previous chunk's LDS reads done
#pragma unroll
      for (int j = 0; j < 2; ++j) {
        float4 v = pa[j];
        aSq += v.x * v.x + v.y * v.y + v.z * v.z + v.w * v.w;
        unsigned int lo = (unsigned int)f2bf(v.x) | ((unsigned int)f2bf(v.y) << 16);
        unsigned int hi = (unsigned int)f2bf(v.z) | ((unsigned int)f2bf(v.w) << 16);
        *(uint2*)&sAh[wslot[j]] = make_uint2(lo, hi);
        float4 t0 = pb0[j];
        b0Sq += t0.x * t0.x + t0.y * t0.y + t0.z * t0.z + t0.w * t0.w;
        lo = (unsigned int)f2bf(t0.x) | ((unsigned int)f2bf(t0.y) << 16);
        hi = (unsigned int)f2bf(t0.z) | ((unsigned int)f2bf(t0.w) << 16);
        *(uint2*)&sBh[0][wslot[j]] = make_uint2(lo, hi);
        float4 t1 = pb1[j];
        b1Sq += t1.x * t1.x + t1.y * t1.y + t1.z * t1.z + t1.w * t1.w;
        lo = (unsigned int)f2bf(t1.x) | ((unsigned int)f2bf(t1.y) << 16);
        hi = (unsigned int)f2bf(t1.z) | ((unsigned int)f2bf(t1.w) << 16);
        *(uint2*)&sBh[1][wslot[j]] = make_uint2(lo, hi);
      }
      __syncthreads();  // tile visible
      if (ch < 31) {    // issue next chunk's loads; latency hides under MFMA
        const float* ap = aRow + (ch + 1) * 64;
        const float* b0p = b0Row + (ch + 1) * 64;
        const float* b1p = b1Row + (ch + 1) * 64;
#pragma unroll
        for (int j = 0; j < 2; ++j) {
          int off = (p + 8 * j) * 4;
          pa[j] = *(const float4*)(ap + off);
          pb0[j] = *(const float4*)(b0p + off);
          pb1[j] = b1val ? *(const float4*)(b1p + off)
                         : make_float4(0.f, 0.f, 0.f, 0.f);
        }
      }
      // compute: 2 k-steps of 32; wave-group grp consumes its B tile
#pragma unroll
      for (int kk = 0; kk < 2; ++kk) {
        int su = kk * 4 + g;
        int arow = w4 * 16 + c;
        bf16x8 af = *(const bf16x8*)&sAh[arow * 64 + (su ^ (arow & 7)) * 8];
#pragma unroll
        for (int f = 0; f < 4; ++f) {
          int brow = f * 16 + c;
          bf16x8 bfr =
              *(const bf16x8*)&sBh[grp][brow * 64 + (su ^ (brow & 7)) * 8];
          acc[f] = __builtin_amdgcn_mfma_f32_16x16x32_bf16(af, bfr, acc[f], 0, 0, 0);
        }
      }
    }

    // exact-f32 row sums of squares: reduce across the 8 p-lanes per row
    aSq += __shfl_down(aSq, 4, 8);
    aSq += __shfl_down(aSq, 2, 8);
    aSq += __shfl_down(aSq, 1, 8);
    b0Sq += __shfl_down(b0Sq, 4, 8);
    b0Sq += __shfl_down(b0Sq, 2, 8);
    b0Sq += __shfl_down(b0Sq, 1, 8);
    b1Sq += __shfl_down(b1Sq, 4, 8);
    b1Sq += __shfl_down(b1Sq, 2, 8);
    b1Sq += __shfl_down(b1Sq, 1, 8);
    if (p == 0) {
      sS2[r] = aSq;
      sN2[0][r] = b0Sq;
      sN2[1][r] = b1Sq;
    }
    __syncthreads();

    if (pair == 0 && tid < SS) ws[WS_S2 + b * SS + tid] = sS2[tid];

    // selection: wave-group grp covers tile tileBase+grp; lane holds
    // C[s][m] for s = w4*16+g*4+reg, m_local = f*16+c
    int tile = tileBase + grp;
#pragma unroll
    for (int reg = 0; reg < 4; ++reg) {
      int s = w4 * 16 + g * 4 + reg;
      int slab = sSlab[s];
      float s2v = sS2[s];
      float posD = -3.4e38f, posC = 0.f, posN = 0.f;
      int posI = -1;
      float negD = 3.4e38f, negC = 0.f, negN = 0.f;
      int negI = -1;
#pragma unroll
      for (int f = 0; f < 4; ++f) {
        int ml = f * 16 + c;
        int lab = sMlab[grp][ml];
        float cv = acc[f][reg];
        float n2 = sN2[grp][ml];
        float d2 = fmaxf(s2v + n2 - 2.f * cv, 0.f);
        if (lab >= 0 && lab == slab && (posI < 0 || d2 > posD)) {
          posD = d2; posI = tile * MT + ml; posC = cv; posN = n2;
        }
        if (lab >= 0 && lab != slab && (negI < 0 || d2 < negD)) {
          negD = d2; negI = tile * MT + ml; negC = cv; negN = n2;
        }
      }
      // tuple reduce across the 16 c-lanes (quarter-wave), JAX tie-break
#pragma unroll
      for (int off = 8; off; off >>= 1) {
        float oD = __shfl_down(posD, off, 16);
        int oI = __shfl_down(posI, off, 16);
        float oC = __shfl_down(posC, off, 16);
        float oN = __shfl_down(posN, off, 16);
        bool take = (oI >= 0) &&
                    (posI < 0 || oD > posD || (oD == posD && oI < posI));
        if (take) { posD = oD; posI = oI; posC = oC; posN = oN; }
        oD = __shfl_down(negD, off, 16);
        oI = __shfl_down(negI, off, 16);
        oC = __shfl_down(negC, off, 16);
        oN = __shfl_down(negN, off, 16);
        take = (oI >= 0) &&
               (negI < 0 || oD < negD || (oD == negD && oI < negI));
        if (take) { negD = oD; negI = oI; negC = oC; negN = oN; }
      }
      if (c == 0) {
        size_t base = (((size_t)b * SS + s) * NT + tile) * 8;
        *(float4*)&ws[WS_CAND + base] =
            make_float4(posD, __int_as_float(posI), posC, posN);
        *(float4*)&ws[WS_CAND + base + 4] =
            make_float4(negD, __int_as_float(negI), negC, negN);
      }
    }
  } else if (bx < TOT_BLOCKS - 1) {
    // ------- feat column-sum: contiguous 47-row unit, 512 threads ------------
    int u = q19 * 16 + (r19 - 3);    // 0..1023
    int tz = u >> 9;                 // 0: act, 1: bkg
    int rem = u & 511;
    int fb = rem >> 4;               // batch
    int sub = rem & 15;              // t-subchunk
    const float* feat = tz ? feat_bkg : feat_act;
    int t0 = sub * FROWS;
    int t1 = t0 + FROWS < TT ? t0 + FROWS : TT;  // 47 rows (last: 45)
    const float* bp = feat + (size_t)fb * TT * DD + tid * 4;

    f32x4 a0 = {0.f, 0.f, 0.f, 0.f}, a1 = {0.f, 0.f, 0.f, 0.f};
    f32x4 a2 = {0.f, 0.f, 0.f, 0.f}, a3 = {0.f, 0.f, 0.f, 0.f};
    int t = t0;
    for (; t + 3 < t1; t += 4) {
      f32x4 v0 = __builtin_nontemporal_load((const f32x4*)(bp + (size_t)t * DD));
      f32x4 v1 =
          __builtin_nontemporal_load((const f32x4*)(bp + (size_t)(t + 1) * DD));
      f32x4 v2 =
          __builtin_nontemporal_load((const f32x4*)(bp + (size_t)(t + 2) * DD));
      f32x4 v3 =
          __builtin_nontemporal_load((const f32x4*)(bp + (size_t)(t + 3) * DD));
      a0 += v0;
      a1 += v1;
      a2 += v2;
      a3 += v3;
    }
    for (; t < t1; ++t)
      a0 += __builtin_nontemporal_load((const f32x4*)(bp + (size_t)t * DD));
    f32x4 rr = (a0 + a2) + (a1 + a3);
    float* cs = ws + WS_COLSUM +
                ((size_t)(tz * BB + fb) * FSPLIT + sub) * DD + tid * 4;
    *(f32x4*)cs = rr;
  } else {
    // ---------------- BCE losses (512 threads) ----------------
    float vc = 0.f, vb = 0.f;
    for (int i = tid; i < BB * CC; i += 512) {
      int b = i / CC, c = i % CC;
      float rs = 0.f;
      for (int k = 0; k < CC; ++k) rs += label[b * CC + k];
      float ln = label[b * CC + c] / rs;
      float pa = score_act[i];
      vc += ln * logf(pa) + (1.f - ln) * logf(1.f - pa);
      float pb = score_bkg[i];
      const float tb = 1.f / (float)CC;
      vb += tb * logf(pb) + (1.f - tb) * logf(1.f - pb);
    }
    for (int off = 32; off; off >>= 1) {
      vc += __shfl_down(vc, off, 64);
      vb += __shfl_down(vb, off, 64);
    }
    __shared__ float rc[8], rb[8];
    if ((tid & 63) == 0) {
      rc[tid >> 6] = vc;
      rb[tid >> 6] = vb;
    }
    __syncthreads();
    if (tid == 0) {
      float sc = 0.f, sb = 0.f;
      for (int k = 0; k < 8; ++k) {
        sc += rc[k];
        sb += rb[k];
      }
      ws[WS_LOSS01] = -sc / (float)(BB * CC);
      ws[WS_LOSS01 + 1] = -sb / (float)(BB * CC);
    }
  }
}

// ---------------------------------------------------------------------------
// Tail: [0,64) feat norm finalize (16 partial rows) | [64,96) gcn combine.
// ---------------------------------------------------------------------------
__global__ __launch_bounds__(256) void tail_kernel(float* __restrict__ ws) {
  int bx = blockIdx.x, tid = threadIdx.x;
  if (bx < 64) {
    int tz = bx >> 5, fb = bx & 31;
    const float* cs = ws + WS_COLSUM + (size_t)(tz * BB + fb) * FSPLIT * DD;
    int d0 = tid * 8;
    float4 A0 = make_float4(0.f, 0.f, 0.f, 0.f);
    float4 A1 = make_float4(0.f, 0.f, 0.f, 0.f);
    for (int blk = 0; blk < FSPLIT; ++blk) {
      const float* pp = cs + blk * DD + d0;
      float4 u = *(const float4*)pp;
      float4 v = *(const float4*)(pp + 4);
      A0.x += u.x; A0.y += u.y; A0.z += u.z; A0.w += u.w;
      A1.x += v.x; A1.y += v.y; A1.z += v.z; A1.w += v.w;
    }
    const float inv = 1.f / (float)TT;
    float m0 = A0.x * inv, m1 = A0.y * inv, m2 = A0.z * inv, m3 = A0.w * inv;
    float m4 = A1.x * inv, m5 = A1.y * inv, m6 = A1.z * inv, m7 = A1.w * inv;
    float v = m0 * m0 + m1 * m1 + m2 * m2 + m3 * m3 +
              m4 * m4 + m5 * m5 + m6 * m6 + m7 * m7;
    for (int off = 32; off; off >>= 1) v += __shfl_down(v, off, 64);
    __shared__ float red[4];
    if ((tid & 63) == 0) red[tid >> 6] = v;
    __syncthreads();
    if (tid == 0)
      ws[(tz ? WS_N2BKG : WS_N2ACT) + fb] = red[0] + red[1] + red[2] + red[3];
  } else {
    int b = bx - 64;
    if (tid < SS) {
      const float* cb = ws + WS_CAND + ((size_t)b * SS + tid) * NT * 8;
      float posD = -3.4e38f, posC = 0.f, posN = 0.f;
      int posI = -1;
      float negD = 3.4e38f, negC = 0.f, negN = 0.f;
      int negI = -1;
      for (int t = 0; t < NT; ++t) {
        float4 pq = *(const float4*)&cb[t * 8];
        int oI = __float_as_int(pq.y);
        if (oI >= 0 && (posI < 0 || pq.x > posD || (pq.x == posD && oI < posI))) {
          posD = pq.x; posI = oI; posC = pq.z; posN = pq.w;
        }
        float4 qq = *(const float4*)&cb[t * 8 + 4];
        oI = __float_as_int(qq.y);
        if (oI >= 0 && (negI < 0 || qq.x < negD || (qq.x == negD && oI < negI))) {
          negD = qq.x; negI = oI; negC = qq.z; negN = qq.w;
        }
      }
      float snorm = sqrtf(ws[WS_S2 + b * SS + tid]);
      float sden = fmaxf(snorm, EPS_V);
      float pl = (posI >= 0) ? posC / (sden * fmaxf(sqrtf(posN), EPS_V)) : 0.f;
      float nl = (negI >= 0) ? negC / (sden * fmaxf(sqrtf(negN), EPS_V)) : 0.f;
      float v = pl + nl;
      for (int off = 32; off; off >>= 1) v += __shfl_down(v, off, 64);
      if (tid == 0) ws[WS_GCNB + b] = v;
    }
  }
}

// ---------------------------------------------------------------------------
// Final deterministic scalar combine.
// ---------------------------------------------------------------------------
__global__ void final_kernel(const float* __restrict__ ws,
                             float* __restrict__ out) {
  int tid = threadIdx.x;  // 64 threads
  float um = 0.f, g = 0.f;
  if (tid < BB) {
    float la = fmaxf(MARGIN_W - sqrtf(ws[WS_N2ACT + tid]), 0.f);
    float lb = sqrtf(ws[WS_N2BKG + tid]);
    um = (la + lb) * (la + lb);
    g = ws[WS_GCNB + tid];
  }
  for (int off = 32; off; off >>= 1) {
    um += __shfl_down(um, off, 64);
    g += __shfl_down(g, off, 64);
  }
  if (tid == 0)
    out[0] = ws[WS_LOSS01] + BETA_W * ws[WS_LOSS01 + 1] +
             ALPHA_W * (um / (float)BB) + GCN_W * g;
}

// ---------------------------------------------------------------------------
extern "C" void kernel_launch(void* const* d_in, const int* in_sizes, int n_in,
                              void* d_out, int out_size, void* d_ws,
                              size_t ws_size, hipStream_t stream) {
  const float* score_act = (const float*)d_in[0];
  const float* score_bkg = (const float*)d_in[1];
  const float* feat_act = (const float*)d_in[2];
  const float* feat_bkg = (const float*)d_in[3];
  const float* label = (const float*)d_in[4];
  // d_in[5] = gt, d_in[6] = cas: unused by the reference loss
  const float* nodes = (const float*)d_in[7];
  const int* nlab = (const int*)d_in[8];
  const int* sidx = (const int*)d_in[9];
  float* out = (float*)d_out;
  float* wsf = (float*)d_ws;

  mega_kernel<<<TOT_BLOCKS, 512, 0, stream>>>(
      score_act, score_bkg, feat_act, feat_bkg, label, nodes, nlab, sidx, wsf);
  tail_kernel<<<96, 256, 0, stream>>>(wsf);
  final_kernel<<<1, 64, 0, stream>>>(wsf, out);
}

// Round 13
// 119.848 us; speedup vs baseline: 1.0729x; 1.0729x over previous
//
#include <hip/hip_runtime.h>
#include <math.h>

// Problem constants (from reference setup_inputs)
#define BB 32
#define TT 750
#define DD 2048
#define CC 20
#define MM 750
#define SS 64
#define MT 64          // gcn m-tile
#define NT 12          // tiles per batch
#define FSPLIT 16      // feat t-subchunks per (tz,fb); 47 rows each
#define FROWS 47
#define FUNITS (2 * BB * FSPLIT)   // 1024 feat blocks

#define GCN_BLOCKS (NT * BB)       // 384
#define TOT_BLOCKS (FUNITS + GCN_BLOCKS + 1)  // 1409

#define ALPHA_W 0.0005f
#define BETA_W 0.1f
#define MARGIN_W 100.0f
#define GCN_W 0.1f
#define EPS_V 1e-8f

// ws float offsets
#define WS_LOSS01 0
#define WS_N2ACT 16
#define WS_N2BKG 48
#define WS_GCNB 80
#define WS_S2 128          // 2048 floats
#define WS_CAND 4096       // 32*64*12*8 = 196608 floats
#define WS_COLSUM 200704   // 2*32*16*2048 = 2097152 floats (ws ~9.2 MB, proven R9)

typedef __attribute__((ext_vector_type(8))) short bf16x8;
typedef __attribute__((ext_vector_type(4))) float f32x4;

// f32 -> bf16 round-to-nearest-even
__device__ __forceinline__ unsigned short f2bf(float f) {
  unsigned int u = __float_as_uint(f);
  return (unsigned short)((u + 0x7FFFu + ((u >> 16) & 1u)) >> 16);
}

// ---------------------------------------------------------------------------
// Mega kernel, FEAT-FIRST block order: bx in [0,1024) -> feat unit;
// [1024,1408) -> gcn tile; 1408 -> bce.
// Model (R6-R12): streaming BW ~ resident streaming waves (~150 GB/s/wave,
// saturates ~32 waves/CU). Feat-first ordering gives a pure-feat opening
// phase at 8 blocks/CU (LDS 17.9KB, VGPR 60 -> 32 waves/CU); gcn blocks
// dispatch as feat drains -> overlap without throttling.
// LEDGER (do not re-try):
//  - (256,6) launch bound: VGPR capped 40 -> gcn spilled; 208us.
//  - feat d-half split (strided spans): 1.78 TB/s. Units must be contiguous.
//  - per-wave MLP levers (ILP-4/8, pipeline+sched_barrier, stealing):
//    all null; per-wave depth is compiler-fixed, VGPR stays 60.
//  - 512-thr pair-block fusion: gcn blocks lengthen -> low-occupancy tail.
//  - PROVEN: feat-alone 512thr/no-LDS = 4.8 TB/s (R11); chip writes 7 TB/s.
// ---------------------------------------------------------------------------
__global__ __launch_bounds__(256, 3) void mega_kernel(
    const float* __restrict__ score_act, const float* __restrict__ score_bkg,
    const float* __restrict__ feat_act, const float* __restrict__ feat_bkg,
    const float* __restrict__ label, const float* __restrict__ nodes,
    const int* __restrict__ nlab, const int* __restrict__ sidx,
    float* __restrict__ ws) {
  int bx = blockIdx.x;
  int tid = threadIdx.x;

  if (bx < FUNITS) {
    // ---- feat column-sum: contiguous 47-row unit, 4 rows x 2 halves/iter ----
    int tz = bx >> 9;                // 0: act, 1: bkg
    int rem = bx & 511;
    int fb = rem >> 4;               // batch
    int sub = rem & 15;              // t-subchunk
    const float* feat = tz ? feat_bkg : feat_act;
    int t0 = sub * FROWS;
    int t1 = t0 + FROWS < TT ? t0 + FROWS : TT;  // 47 rows (last: 45)
    const float* bp = feat + (size_t)fb * TT * DD + tid * 4;
    f32x4 a00 = {0.f, 0.f, 0.f, 0.f}, a01 = {0.f, 0.f, 0.f, 0.f};
    f32x4 a10 = {0.f, 0.f, 0.f, 0.f}, a11 = {0.f, 0.f, 0.f, 0.f};
    f32x4 a20 = {0.f, 0.f, 0.f, 0.f}, a21 = {0.f, 0.f, 0.f, 0.f};
    f32x4 a30 = {0.f, 0.f, 0.f, 0.f}, a31 = {0.f, 0.f, 0.f, 0.f};
    int t = t0;
    for (; t + 3 < t1; t += 4) {  // 8 independent nontemporal loads in flight
      const f32x4* p0 = (const f32x4*)(bp + (size_t)t * DD);
      const f32x4* p1 = (const f32x4*)(bp + (size_t)(t + 1) * DD);
      const f32x4* p2 = (const f32x4*)(bp + (size_t)(t + 2) * DD);
      const f32x4* p3 = (const f32x4*)(bp + (size_t)(t + 3) * DD);
      f32x4 v00 = __builtin_nontemporal_load(p0);
      f32x4 v01 = __builtin_nontemporal_load(p0 + 256);
      f32x4 v10 = __builtin_nontemporal_load(p1);
      f32x4 v11 = __builtin_nontemporal_load(p1 + 256);
      f32x4 v20 = __builtin_nontemporal_load(p2);
      f32x4 v21 = __builtin_nontemporal_load(p2 + 256);
      f32x4 v30 = __builtin_nontemporal_load(p3);
      f32x4 v31 = __builtin_nontemporal_load(p3 + 256);
      a00 += v00; a01 += v01;
      a10 += v10; a11 += v11;
      a20 += v20; a21 += v21;
      a30 += v30; a31 += v31;
    }
    for (; t < t1; ++t) {  // remainder (47%4==3; last 45%4==1)
      const f32x4* p0 = (const f32x4*)(bp + (size_t)t * DD);
      a00 += __builtin_nontemporal_load(p0);
      a01 += __builtin_nontemporal_load(p0 + 256);
    }
    f32x4 r0 = (a00 + a10) + (a20 + a30);
    f32x4 r1 = (a01 + a11) + (a21 + a31);
    float* cs = ws + WS_COLSUM +
                ((size_t)(tz * BB + fb) * FSPLIT + sub) * DD + tid * 4;
    *(f32x4*)cs = r0;
    *(f32x4*)(cs + 1024) = r1;
  } else if (bx < FUNITS + GCN_BLOCKS) {
    // ---------------- GCN tile: batch b, 64-m tile, bf16 MFMA ----------------
    int idx = bx - FUNITS;
    int b = idx / NT, tile = idx % NT;

    // LDS: bf16 tiles, 64 rows x 64 k each; rows = 128B = 8 16B-units,
    // XOR-swizzled by (row&7) on the 16B unit index.
    __shared__ __align__(16) unsigned short sAh[64 * 64];
    __shared__ __align__(16) unsigned short sBh[64 * 64];
    __shared__ float sS2[SS];
    __shared__ float sN2[MT];
    __shared__ int sSlab[SS];
    __shared__ int sMlab[MT];

    if (tid < SS) {
      sSlab[tid] = nlab[b * MM + sidx[b * SS + tid]];
    } else if (tid < SS + MT) {
      int ml = tid - SS;
      int m = tile * MT + ml;
      sMlab[ml] = (m < MM) ? nlab[b * MM + m] : -2;
    }

    // staging: thread -> row r = tid>>2 (both A-s-row and B-m-row), p = tid&3,
    // covering 8B-granules u = p+4j (j=0..3) of the 64-f32 chunk row.
    int r = tid >> 2, p = tid & 3;
    const float* aRow = nodes + ((size_t)b * MM + sidx[b * SS + r]) * DD;
    int mrow = tile * MT + r;
    bool bval = (mrow < MM);
    const float* bRow = nodes + ((size_t)b * MM + (bval ? mrow : 0)) * DD;

    int wslot[4];  // ushort index of the 8B granule in the swizzled row
#pragma unroll
    for (int j = 0; j < 4; ++j) {
      int u = p + 4 * j;
      wslot[j] = r * 64 + ((((u >> 1) ^ (r & 7)) << 1) + (u & 1)) * 4;
    }

    int lane = tid & 63, w = tid >> 6;
    int g = lane >> 4, c = lane & 15;

    float aSq = 0.f, bSq = 0.f;
    f32x4 acc[4];
#pragma unroll
    for (int f = 0; f < 4; ++f) acc[f] = (f32x4){0.f, 0.f, 0.f, 0.f};

    // prefetch chunk 0
    float4 pa[4], pb[4];
#pragma unroll
    for (int j = 0; j < 4; ++j) {
      int off = (p + 4 * j) * 4;
      pa[j] = *(const float4*)(aRow + off);
      pb[j] = *(const float4*)(bRow + off);
    }

    for (int ch = 0; ch < 32; ++ch) {
      __syncthreads();  // previous chunk's LDS reads done
#pragma unroll
      for (int j = 0; j < 4; ++j) {
        float4 v = pa[j];
        aSq += v.x * v.x + v.y * v.y + v.z * v.z + v.w * v.w;
        unsigned int lo = (unsigned int)f2bf(v.x) | ((unsigned int)f2bf(v.y) << 16);
        unsigned int hi = (unsigned int)f2bf(v.z) | ((unsigned int)f2bf(v.w) << 16);
        *(uint2*)&sAh[wslot[j]] = make_uint2(lo, hi);
        float4 t = pb[j];
        bSq += t.x * t.x + t.y * t.y + t.z * t.z + t.w * t.w;
        lo = (unsigned int)f2bf(t.x) | ((unsigned int)f2bf(t.y) << 16);
        hi = (unsigned int)f2bf(t.z) | ((unsigned int)f2bf(t.w) << 16);
        *(uint2*)&sBh[wslot[j]] = make_uint2(lo, hi);
      }
      __syncthreads();  // tile visible
      if (ch < 31) {    // issue next chunk's loads; latency hides under MFMA
        const float* ap = aRow + (ch + 1) * 64;
        const float* bp2 = bRow + (ch + 1) * 64;
#pragma unroll
        for (int j = 0; j < 4; ++j) {
          int off = (p + 4 * j) * 4;
          pa[j] = *(const float4*)(ap + off);
          pb[j] = *(const float4*)(bp2 + off);
        }
      }
      // compute: 2 k-steps of 32 over the 64-k chunk
#pragma unroll
      for (int kk = 0; kk < 2; ++kk) {
        int su = kk * 4 + g;
        int arow = w * 16 + c;
        bf16x8 af = *(const bf16x8*)&sAh[arow * 64 + (su ^ (arow & 7)) * 8];
#pragma unroll
        for (int f = 0; f < 4; ++f) {
          int brow = f * 16 + c;
          bf16x8 bfr = *(const bf16x8*)&sBh[brow * 64 + (su ^ (brow & 7)) * 8];
          acc[f] = __builtin_amdgcn_mfma_f32_16x16x32_bf16(af, bfr, acc[f], 0, 0, 0);
        }
      }
    }

    // exact-f32 row sums of squares: reduce across the 4 p-lanes per row
    aSq += __shfl_down(aSq, 2, 4);
    aSq += __shfl_down(aSq, 1, 4);
    bSq += __shfl_down(bSq, 2, 4);
    bSq += __shfl_down(bSq, 1, 4);
    if (p == 0) {
      sS2[r] = aSq;
      sN2[r] = bSq;
    }
    __syncthreads();

    if (tile == 0 && tid < SS) ws[WS_S2 + b * SS + tid] = sS2[tid];

    // selection: lane holds C[s][m] for s = w*16+g*4+reg, m_local = f*16+c
#pragma unroll
    for (int reg = 0; reg < 4; ++reg) {
      int s = w * 16 + g * 4 + reg;
      int slab = sSlab[s];
      float s2v = sS2[s];
      float posD = -3.4e38f, posC = 0.f, posN = 0.f;
      int posI = -1;
      float negD = 3.4e38f, negC = 0.f, negN = 0.f;
      int negI = -1;
#pragma unroll
      for (int f = 0; f < 4; ++f) {
        int ml = f * 16 + c;
        int lab = sMlab[ml];
        float cv = acc[f][reg];
        float n2 = sN2[ml];
        float d2 = fmaxf(s2v + n2 - 2.f * cv, 0.f);
        if (lab >= 0 && lab == slab && (posI < 0 || d2 > posD)) {
          posD = d2; posI = tile * MT + ml; posC = cv; posN = n2;
        }
        if (lab >= 0 && lab != slab && (negI < 0 || d2 < negD)) {
          negD = d2; negI = tile * MT + ml; negC = cv; negN = n2;
        }
      }
      // tuple reduce across the 16 c-lanes (quarter-wave), JAX tie-break
#pragma unroll
      for (int off = 8; off; off >>= 1) {
        float oD = __shfl_down(posD, off, 16);
        int oI = __shfl_down(posI, off, 16);
        float oC = __shfl_down(posC, off, 16);
        float oN = __shfl_down(posN, off, 16);
        bool take = (oI >= 0) &&
                    (posI < 0 || oD > posD || (oD == posD && oI < posI));
        if (take) { posD = oD; posI = oI; posC = oC; posN = oN; }
        oD = __shfl_down(negD, off, 16);
        oI = __shfl_down(negI, off, 16);
        oC = __shfl_down(negC, off, 16);
        oN = __shfl_down(negN, off, 16);
        take = (oI >= 0) &&
               (negI < 0 || oD < negD || (oD == negD && oI < negI));
        if (take) { negD = oD; negI = oI; negC = oC; negN = oN; }
      }
      if (c == 0) {
        size_t base = (((size_t)b * SS + s) * NT + tile) * 8;
        *(float4*)&ws[WS_CAND + base] =
            make_float4(posD, __int_as_float(posI), posC, posN);
        *(float4*)&ws[WS_CAND + base + 4] =
            make_float4(negD, __int_as_float(negI), negC, negN);
      }
    }
  } else {
    // ---------------- BCE losses ----------------
    float vc = 0.f, vb = 0.f;
    for (int i = tid; i < BB * CC; i += 256) {
      int b = i / CC, c = i % CC;
      float rs = 0.f;
      for (int k = 0; k < CC; ++k) rs += label[b * CC + k];
      float ln = label[b * CC + c] / rs;
      float pa = score_act[i];
      vc += ln * logf(pa) + (1.f - ln) * logf(1.f - pa);
      float pb = score_bkg[i];
      const float tb = 1.f / (float)CC;
      vb += tb * logf(pb) + (1.f - tb) * logf(1.f - pb);
    }
    for (int off = 32; off; off >>= 1) {
      vc += __shfl_down(vc, off, 64);
      vb += __shfl_down(vb, off, 64);
    }
    __shared__ float rc[4], rb[4];
    if ((tid & 63) == 0) {
      rc[tid >> 6] = vc;
      rb[tid >> 6] = vb;
    }
    __syncthreads();
    if (tid == 0) {
      ws[WS_LOSS01] = -(rc[0] + rc[1] + rc[2] + rc[3]) / (float)(BB * CC);
      ws[WS_LOSS01 + 1] = -(rb[0] + rb[1] + rb[2] + rb[3]) / (float)(BB * CC);
    }
  }
}

// ---------------------------------------------------------------------------
// Tail: [0,64) feat norm finalize (16 partial rows) | [64,96) gcn combine.
// ---------------------------------------------------------------------------
__global__ __launch_bounds__(256) void tail_kernel(float* __restrict__ ws) {
  int bx = blockIdx.x, tid = threadIdx.x;
  if (bx < 64) {
    int tz = bx >> 5, fb = bx & 31;
    const float* cs = ws + WS_COLSUM + (size_t)(tz * BB + fb) * FSPLIT * DD;
    int d0 = tid * 8;
    float4 A0 = make_float4(0.f, 0.f, 0.f, 0.f);
    float4 A1 = make_float4(0.f, 0.f, 0.f, 0.f);
    for (int blk = 0; blk < FSPLIT; ++blk) {
      const float* pp = cs + blk * DD + d0;
      float4 u = *(const float4*)pp;
      float4 v = *(const float4*)(pp + 4);
      A0.x += u.x; A0.y += u.y; A0.z += u.z; A0.w += u.w;
      A1.x += v.x; A1.y += v.y; A1.z += v.z; A1.w += v.w;
    }
    const float inv = 1.f / (float)TT;
    float m0 = A0.x * inv, m1 = A0.y * inv, m2 = A0.z * inv, m3 = A0.w * inv;
    float m4 = A1.x * inv, m5 = A1.y * inv, m6 = A1.z * inv, m7 = A1.w * inv;
    float v = m0 * m0 + m1 * m1 + m2 * m2 + m3 * m3 +
              m4 * m4 + m5 * m5 + m6 * m6 + m7 * m7;
    for (int off = 32; off; off >>= 1) v += __shfl_down(v, off, 64);
    __shared__ float red[4];
    if ((tid & 63) == 0) red[tid >> 6] = v;
    __syncthreads();
    if (tid == 0)
      ws[(tz ? WS_N2BKG : WS_N2ACT) + fb] = red[0] + red[1] + red[2] + red[3];
  } else {
    int b = bx - 64;
    if (tid < SS) {
      const float* cb = ws + WS_CAND + ((size_t)b * SS + tid) * NT * 8;
      float posD = -3.4e38f, posC = 0.f, posN = 0.f;
      int posI = -1;
      float negD = 3.4e38f, negC = 0.f, negN = 0.f;
      int negI = -1;
      for (int t = 0; t < NT; ++t) {
        float4 pq = *(const float4*)&cb[t * 8];
        int oI = __float_as_int(pq.y);
        if (oI >= 0 && (posI < 0 || pq.x > posD || (pq.x == posD && oI < posI))) {
          posD = pq.x; posI = oI; posC = pq.z; posN = pq.w;
        }
        float4 qq = *(const float4*)&cb[t * 8 + 4];
        oI = __float_as_int(qq.y);
        if (oI >= 0 && (negI < 0 || qq.x < negD || (qq.x == negD && oI < negI))) {
          negD = qq.x; negI = oI; negC = qq.z; negN = qq.w;
        }
      }
      float snorm = sqrtf(ws[WS_S2 + b * SS + tid]);
      float sden = fmaxf(snorm, EPS_V);
      float pl = (posI >= 0) ? posC / (sden * fmaxf(sqrtf(posN), EPS_V)) : 0.f;
      float nl = (negI >= 0) ? negC / (sden * fmaxf(sqrtf(negN), EPS_V)) : 0.f;
      float v = pl + nl;
      for (int off = 32; off; off >>= 1) v += __shfl_down(v, off, 64);
      if (tid == 0) ws[WS_GCNB + b] = v;
    }
  }
}

// ---------------------------------------------------------------------------
// Final deterministic scalar combine.
// ---------------------------------------------------------------------------
__global__ void final_kernel(const float* __restrict__ ws,
                             float* __restrict__ out) {
  int tid = threadIdx.x;  // 64 threads
  float um = 0.f, g = 0.f;
  if (tid < BB) {
    float la = fmaxf(MARGIN_W - sqrtf(ws[WS_N2ACT + tid]), 0.f);
    float lb = sqrtf(ws[WS_N2BKG + tid]);
    um = (la + lb) * (la + lb);
    g = ws[WS_GCNB + tid];
  }
  for (int off = 32; off; off >>= 1) {
    um += __shfl_down(um, off, 64);
    g += __shfl_down(g, off, 64);
  }
  if (tid == 0)
    out[0] = ws[WS_LOSS01] + BETA_W * ws[WS_LOSS01 + 1] +
             ALPHA_W * (um / (float)BB) + GCN_W * g;
}

// ---------------------------------------------------------------------------
extern "C" void kernel_launch(void* const* d_in, const int* in_sizes, int n_in,
                              void* d_out, int out_size, void* d_ws,
                              size_t ws_size, hipStream_t stream) {
  const float* score_act = (const float*)d_in[0];
  const float* score_bkg = (const float*)d_in[1];
  const float* feat_act = (const float*)d_in[2];
  const float* feat_bkg = (const float*)d_in[3];
  const float* label = (const float*)d_in[4];
  // d_in[5] = gt, d_in[6] = cas: unused by the reference loss
  const float* nodes = (const float*)d_in[7];
  const int* nlab = (const int*)d_in[8];
  const int* sidx = (const int*)d_in[9];
  float* out = (float*)d_out;
  float* wsf = (float*)d_ws;

  mega_kernel<<<TOT_BLOCKS, 256, 0, stream>>>(
      score_act, score_bkg, feat_act, feat_bkg, label, nodes, nlab, sidx, wsf);
  tail_kernel<<<96, 256, 0, stream>>>(wsf);
  final_kernel<<<1, 64, 0, stream>>>(wsf, out);
}

// Round 14
// 116.180 us; speedup vs baseline: 1.1068x; 1.0316x over previous
//
#include <hip/hip_runtime.h>
#include <math.h>

// Problem constants (from reference setup_inputs)
#define BB 32
#define TT 750
#define DD 2048
#define CC 20
#define MM 750
#define SS 64
#define MT 64          // gcn m-tile
#define NT 12          // tiles per batch
#define FSPLIT 32      // feat t-subchunks per (tz,fb); 24 rows each (last 6)
#define FROWS 24
#define FUNITS (2 * BB * FSPLIT)   // 2048 feat blocks -> 8 blocks/CU possible

#define GCN_BLOCKS (NT * BB)       // 384
#define TOT_BLOCKS (GCN_BLOCKS + FUNITS + 1)  // 2433

#define ALPHA_W 0.0005f
#define BETA_W 0.1f
#define MARGIN_W 100.0f
#define GCN_W 0.1f
#define EPS_V 1e-8f

// ws float offsets
#define WS_LOSS01 0
#define WS_N2ACT 16
#define WS_N2BKG 48
#define WS_GCNB 80
#define WS_S2 128          // 2048 floats
#define WS_CAND 4096       // 32*64*12*8 = 196608 floats
#define WS_COLSUM 200704   // 2*32*32*2048 = 4194304 floats (ws ~17.6 MB)

typedef __attribute__((ext_vector_type(8))) short bf16x8;
typedef __attribute__((ext_vector_type(4))) float f32x4;

// f32 -> bf16 round-to-nearest-even
__device__ __forceinline__ unsigned short f2bf(float f) {
  unsigned int u = __float_as_uint(f);
  return (unsigned short)((u + 0x7FFFu + ((u >> 16) & 1u)) >> 16);
}

// ---------------------------------------------------------------------------
// Mega kernel, GCN-FIRST order: bx in [0,384) -> gcn tile; [384,2432) -> feat
// unit; 2432 -> bce.
// Model (R6-R13, calibrated): streaming BW ~ resident streaming waves
// (saturates ~32 waves/CU at ~4.8 TB/s, R11). R13's feat phase had only 1024
// blocks = 4 blocks/CU = 16 waves -> 2.4 TB/s. FSPLIT 32 doubles feat block
// density (8 blocks/CU reachable: LDS 17.9KB -> 8, VGPR 60 -> 8 waves/SIMD);
// gcn-first spreads the 384 MFMA blocks ~1.5/CU so they overlap streaming
// from t=0 and feat keeps all retiring slots full to the end.
// LEDGER (do not re-try):
//  - (256,6) launch bound: VGPR capped 40 -> gcn spilled; 208us.
//  - feat d-half split (strided spans): 1.78 TB/s. Units must be contiguous.
//  - per-wave MLP levers (ILP-4/8, pipeline+sched_barrier, stealing): null;
//    per-wave depth is compiler-fixed (VGPR pinned 60).
//  - 512-thr pair-block fusion: gcn lengthens -> low-occupancy tail; 128us.
//  - PROVEN: feat-alone 512thr/no-LDS 32 waves/CU = 4.8 TB/s (R11).
// ---------------------------------------------------------------------------
__global__ __launch_bounds__(256, 3) void mega_kernel(
    const float* __restrict__ score_act, const float* __restrict__ score_bkg,
    const float* __restrict__ feat_act, const float* __restrict__ feat_bkg,
    const float* __restrict__ label, const float* __restrict__ nodes,
    const int* __restrict__ nlab, const int* __restrict__ sidx,
    float* __restrict__ ws) {
  int bx = blockIdx.x;
  int tid = threadIdx.x;

  if (bx < GCN_BLOCKS) {
    // ---------------- GCN tile: batch b, 64-m tile, bf16 MFMA ----------------
    int b = bx / NT, tile = bx % NT;

    // LDS: bf16 tiles, 64 rows x 64 k each; rows = 128B = 8 16B-units,
    // XOR-swizzled by (row&7) on the 16B unit index.
    __shared__ __align__(16) unsigned short sAh[64 * 64];
    __shared__ __align__(16) unsigned short sBh[64 * 64];
    __shared__ float sS2[SS];
    __shared__ float sN2[MT];
    __shared__ int sSlab[SS];
    __shared__ int sMlab[MT];

    if (tid < SS) {
      sSlab[tid] = nlab[b * MM + sidx[b * SS + tid]];
    } else if (tid < SS + MT) {
      int ml = tid - SS;
      int m = tile * MT + ml;
      sMlab[ml] = (m < MM) ? nlab[b * MM + m] : -2;
    }

    // staging: thread -> row r = tid>>2 (both A-s-row and B-m-row), p = tid&3,
    // covering 8B-granules u = p+4j (j=0..3) of the 64-f32 chunk row.
    int r = tid >> 2, p = tid & 3;
    const float* aRow = nodes + ((size_t)b * MM + sidx[b * SS + r]) * DD;
    int mrow = tile * MT + r;
    bool bval = (mrow < MM);
    const float* bRow = nodes + ((size_t)b * MM + (bval ? mrow : 0)) * DD;

    int wslot[4];  // ushort index of the 8B granule in the swizzled row
#pragma unroll
    for (int j = 0; j < 4; ++j) {
      int u = p + 4 * j;
      wslot[j] = r * 64 + ((((u >> 1) ^ (r & 7)) << 1) + (u & 1)) * 4;
    }

    int lane = tid & 63, w = tid >> 6;
    int g = lane >> 4, c = lane & 15;

    float aSq = 0.f, bSq = 0.f;
    f32x4 acc[4];
#pragma unroll
    for (int f = 0; f < 4; ++f) acc[f] = (f32x4){0.f, 0.f, 0.f, 0.f};

    // prefetch chunk 0
    float4 pa[4], pb[4];
#pragma unroll
    for (int j = 0; j < 4; ++j) {
      int off = (p + 4 * j) * 4;
      pa[j] = *(const float4*)(aRow + off);
      pb[j] = *(const float4*)(bRow + off);
    }

    for (int ch = 0; ch < 32; ++ch) {
      __syncthreads();  // previous chunk's LDS reads done
#pragma unroll
      for (int j = 0; j < 4; ++j) {
        float4 v = pa[j];
        aSq += v.x * v.x + v.y * v.y + v.z * v.z + v.w * v.w;
        unsigned int lo = (unsigned int)f2bf(v.x) | ((unsigned int)f2bf(v.y) << 16);
        unsigned int hi = (unsigned int)f2bf(v.z) | ((unsigned int)f2bf(v.w) << 16);
        *(uint2*)&sAh[wslot[j]] = make_uint2(lo, hi);
        float4 t = pb[j];
        bSq += t.x * t.x + t.y * t.y + t.z * t.z + t.w * t.w;
        lo = (unsigned int)f2bf(t.x) | ((unsigned int)f2bf(t.y) << 16);
        hi = (unsigned int)f2bf(t.z) | ((unsigned int)f2bf(t.w) << 16);
        *(uint2*)&sBh[wslot[j]] = make_uint2(lo, hi);
      }
      __syncthreads();  // tile visible
      if (ch < 31) {    // issue next chunk's loads; latency hides under MFMA
        const float* ap = aRow + (ch + 1) * 64;
        const float* bp2 = bRow + (ch + 1) * 64;
#pragma unroll
        for (int j = 0; j < 4; ++j) {
          int off = (p + 4 * j) * 4;
          pa[j] = *(const float4*)(ap + off);
          pb[j] = *(const float4*)(bp2 + off);
        }
      }
      // compute: 2 k-steps of 32 over the 64-k chunk
#pragma unroll
      for (int kk = 0; kk < 2; ++kk) {
        int su = kk * 4 + g;
        int arow = w * 16 + c;
        bf16x8 af = *(const bf16x8*)&sAh[arow * 64 + (su ^ (arow & 7)) * 8];
#pragma unroll
        for (int f = 0; f < 4; ++f) {
          int brow = f * 16 + c;
          bf16x8 bfr = *(const bf16x8*)&sBh[brow * 64 + (su ^ (brow & 7)) * 8];
          acc[f] = __builtin_amdgcn_mfma_f32_16x16x32_bf16(af, bfr, acc[f], 0, 0, 0);
        }
      }
    }

    // exact-f32 row sums of squares: reduce across the 4 p-lanes per row
    aSq += __shfl_down(aSq, 2, 4);
    aSq += __shfl_down(aSq, 1, 4);
    bSq += __shfl_down(bSq, 2, 4);
    bSq += __shfl_down(bSq, 1, 4);
    if (p == 0) {
      sS2[r] = aSq;
      sN2[r] = bSq;
    }
    __syncthreads();

    if (tile == 0 && tid < SS) ws[WS_S2 + b * SS + tid] = sS2[tid];

    // selection: lane holds C[s][m] for s = w*16+g*4+reg, m_local = f*16+c
#pragma unroll
    for (int reg = 0; reg < 4; ++reg) {
      int s = w * 16 + g * 4 + reg;
      int slab = sSlab[s];
      float s2v = sS2[s];
      float posD = -3.4e38f, posC = 0.f, posN = 0.f;
      int posI = -1;
      float negD = 3.4e38f, negC = 0.f, negN = 0.f;
      int negI = -1;
#pragma unroll
      for (int f = 0; f < 4; ++f) {
        int ml = f * 16 + c;
        int lab = sMlab[ml];
        float cv = acc[f][reg];
        float n2 = sN2[ml];
        float d2 = fmaxf(s2v + n2 - 2.f * cv, 0.f);
        if (lab >= 0 && lab == slab && (posI < 0 || d2 > posD)) {
          posD = d2; posI = tile * MT + ml; posC = cv; posN = n2;
        }
        if (lab >= 0 && lab != slab && (negI < 0 || d2 < negD)) {
          negD = d2; negI = tile * MT + ml; negC = cv; negN = n2;
        }
      }
      // tuple reduce across the 16 c-lanes (quarter-wave), JAX tie-break
#pragma unroll
      for (int off = 8; off; off >>= 1) {
        float oD = __shfl_down(posD, off, 16);
        int oI = __shfl_down(posI, off, 16);
        float oC = __shfl_down(posC, off, 16);
        float oN = __shfl_down(posN, off, 16);
        bool take = (oI >= 0) &&
                    (posI < 0 || oD > posD || (oD == posD && oI < posI));
        if (take) { posD = oD; posI = oI; posC = oC; posN = oN; }
        oD = __shfl_down(negD, off, 16);
        oI = __shfl_down(negI, off, 16);
        oC = __shfl_down(negC, off, 16);
        oN = __shfl_down(negN, off, 16);
        take = (oI >= 0) &&
               (negI < 0 || oD < negD || (oD == negD && oI < negI));
        if (take) { negD = oD; negI = oI; negC = oC; negN = oN; }
      }
      if (c == 0) {
        size_t base = (((size_t)b * SS + s) * NT + tile) * 8;
        *(float4*)&ws[WS_CAND + base] =
            make_float4(posD, __int_as_float(posI), posC, posN);
        *(float4*)&ws[WS_CAND + base + 4] =
            make_float4(negD, __int_as_float(negI), negC, negN);
      }
    }
  } else if (bx < GCN_BLOCKS + FUNITS) {
    // ---- feat column-sum: contiguous 24-row unit, 4 rows x 2 halves/iter ----
    int u = bx - GCN_BLOCKS;         // 0..2047
    int tz = u >> 10;                // 0: act, 1: bkg
    int rem = u & 1023;
    int fb = rem >> 5;               // batch
    int sub = rem & 31;              // t-subchunk
    const float* feat = tz ? feat_bkg : feat_act;
    int t0 = sub * FROWS;
    int t1 = t0 + FROWS < TT ? t0 + FROWS : TT;  // 24 rows (last: 6)
    const float* bp = feat + (size_t)fb * TT * DD + tid * 4;
    f32x4 a00 = {0.f, 0.f, 0.f, 0.f}, a01 = {0.f, 0.f, 0.f, 0.f};
    f32x4 a10 = {0.f, 0.f, 0.f, 0.f}, a11 = {0.f, 0.f, 0.f, 0.f};
    f32x4 a20 = {0.f, 0.f, 0.f, 0.f}, a21 = {0.f, 0.f, 0.f, 0.f};
    f32x4 a30 = {0.f, 0.f, 0.f, 0.f}, a31 = {0.f, 0.f, 0.f, 0.f};
    int t = t0;
    for (; t + 3 < t1; t += 4) {  // 8 independent nontemporal loads in flight
      const f32x4* p0 = (const f32x4*)(bp + (size_t)t * DD);
      const f32x4* p1 = (const f32x4*)(bp + (size_t)(t + 1) * DD);
      const f32x4* p2 = (const f32x4*)(bp + (size_t)(t + 2) * DD);
      const f32x4* p3 = (const f32x4*)(bp + (size_t)(t + 3) * DD);
      f32x4 v00 = __builtin_nontemporal_load(p0);
      f32x4 v01 = __builtin_nontemporal_load(p0 + 256);
      f32x4 v10 = __builtin_nontemporal_load(p1);
      f32x4 v11 = __builtin_nontemporal_load(p1 + 256);
      f32x4 v20 = __builtin_nontemporal_load(p2);
      f32x4 v21 = __builtin_nontemporal_load(p2 + 256);
      f32x4 v30 = __builtin_nontemporal_load(p3);
      f32x4 v31 = __builtin_nontemporal_load(p3 + 256);
      a00 += v00; a01 += v01;
      a10 += v10; a11 += v11;
      a20 += v20; a21 += v21;
      a30 += v30; a31 += v31;
    }
    for (; t < t1; ++t) {  // remainder (24%4==0; last unit 6%4==2)
      const f32x4* p0 = (const f32x4*)(bp + (size_t)t * DD);
      a00 += __builtin_nontemporal_load(p0);
      a01 += __builtin_nontemporal_load(p0 + 256);
    }
    f32x4 r0 = (a00 + a10) + (a20 + a30);
    f32x4 r1 = (a01 + a11) + (a21 + a31);
    float* cs = ws + WS_COLSUM +
                ((size_t)(tz * BB + fb) * FSPLIT + sub) * DD + tid * 4;
    *(f32x4*)cs = r0;
    *(f32x4*)(cs + 1024) = r1;
  } else {
    // ---------------- BCE losses ----------------
    float vc = 0.f, vb = 0.f;
    for (int i = tid; i < BB * CC; i += 256) {
      int b = i / CC, c = i % CC;
      float rs = 0.f;
      for (int k = 0; k < CC; ++k) rs += label[b * CC + k];
      float ln = label[b * CC + c] / rs;
      float pa = score_act[i];
      vc += ln * logf(pa) + (1.f - ln) * logf(1.f - pa);
      float pb = score_bkg[i];
      const float tb = 1.f / (float)CC;
      vb += tb * logf(pb) + (1.f - tb) * logf(1.f - pb);
    }
    for (int off = 32; off; off >>= 1) {
      vc += __shfl_down(vc, off, 64);
      vb += __shfl_down(vb, off, 64);
    }
    __shared__ float rc[4], rb[4];
    if ((tid & 63) == 0) {
      rc[tid >> 6] = vc;
      rb[tid >> 6] = vb;
    }
    __syncthreads();
    if (tid == 0) {
      ws[WS_LOSS01] = -(rc[0] + rc[1] + rc[2] + rc[3]) / (float)(BB * CC);
      ws[WS_LOSS01 + 1] = -(rb[0] + rb[1] + rb[2] + rb[3]) / (float)(BB * CC);
    }
  }
}

// ---------------------------------------------------------------------------
// Tail: [0,64) feat norm finalize (32 partial rows) | [64,96) gcn combine.
// ---------------------------------------------------------------------------
__global__ __launch_bounds__(256) void tail_kernel(float* __restrict__ ws) {
  int bx = blockIdx.x, tid = threadIdx.x;
  if (bx < 64) {
    int tz = bx >> 5, fb = bx & 31;
    const float* cs = ws + WS_COLSUM + (size_t)(tz * BB + fb) * FSPLIT * DD;
    int d0 = tid * 8;
    float4 A0 = make_float4(0.f, 0.f, 0.f, 0.f);
    float4 A1 = make_float4(0.f, 0.f, 0.f, 0.f);
    for (int blk = 0; blk < FSPLIT; ++blk) {
      const float* pp = cs + blk * DD + d0;
      float4 u = *(const float4*)pp;
      float4 v = *(const float4*)(pp + 4);
      A0.x += u.x; A0.y += u.y; A0.z += u.z; A0.w += u.w;
      A1.x += v.x; A1.y += v.y; A1.z += v.z; A1.w += v.w;
    }
    const float inv = 1.f / (float)TT;
    float m0 = A0.x * inv, m1 = A0.y * inv, m2 = A0.z * inv, m3 = A0.w * inv;
    float m4 = A1.x * inv, m5 = A1.y * inv, m6 = A1.z * inv, m7 = A1.w * inv;
    float v = m0 * m0 + m1 * m1 + m2 * m2 + m3 * m3 +
              m4 * m4 + m5 * m5 + m6 * m6 + m7 * m7;
    for (int off = 32; off; off >>= 1) v += __shfl_down(v, off, 64);
    __shared__ float red[4];
    if ((tid & 63) == 0) red[tid >> 6] = v;
    __syncthreads();
    if (tid == 0)
      ws[(tz ? WS_N2BKG : WS_N2ACT) + fb] = red[0] + red[1] + red[2] + red[3];
  } else {
    int b = bx - 64;
    if (tid < SS) {
      const float* cb = ws + WS_CAND + ((size_t)b * SS + tid) * NT * 8;
      float posD = -3.4e38f, posC = 0.f, posN = 0.f;
      int posI = -1;
      float negD = 3.4e38f, negC = 0.f, negN = 0.f;
      int negI = -1;
      for (int t = 0; t < NT; ++t) {
        float4 pq = *(const float4*)&cb[t * 8];
        int oI = __float_as_int(pq.y);
        if (oI >= 0 && (posI < 0 || pq.x > posD || (pq.x == posD && oI < posI))) {
          posD = pq.x; posI = oI; posC = pq.z; posN = pq.w;
        }
        float4 qq = *(const float4*)&cb[t * 8 + 4];
        oI = __float_as_int(qq.y);
        if (oI >= 0 && (negI < 0 || qq.x < negD || (qq.x == negD && oI < negI))) {
          negD = qq.x; negI = oI; negC = qq.z; negN = qq.w;
        }
      }
      float snorm = sqrtf(ws[WS_S2 + b * SS + tid]);
      float sden = fmaxf(snorm, EPS_V);
      float pl = (posI >= 0) ? posC / (sden * fmaxf(sqrtf(posN), EPS_V)) : 0.f;
      float nl = (negI >= 0) ? negC / (sden * fmaxf(sqrtf(negN), EPS_V)) : 0.f;
      float v = pl + nl;
      for (int off = 32; off; off >>= 1) v += __shfl_down(v, off, 64);
      if (tid == 0) ws[WS_GCNB + b] = v;
    }
  }
}

// ---------------------------------------------------------------------------
// Final deterministic scalar combine.
// ---------------------------------------------------------------------------
__global__ void final_kernel(const float* __restrict__ ws,
                             float* __restrict__ out) {
  int tid = threadIdx.x;  // 64 threads
  float um = 0.f, g = 0.f;
  if (tid < BB) {
    float la = fmaxf(MARGIN_W - sqrtf(ws[WS_N2ACT + tid]), 0.f);
    float lb = sqrtf(ws[WS_N2BKG + tid]);
    um = (la + lb) * (la + lb);
    g = ws[WS_GCNB + tid];
  }
  for (int off = 32; off; off >>= 1) {
    um += __shfl_down(um, off, 64);
    g += __shfl_down(g, off, 64);
  }
  if (tid == 0)
    out[0] = ws[WS_LOSS01] + BETA_W * ws[WS_LOSS01 + 1] +
             ALPHA_W * (um / (float)BB) + GCN_W * g;
}

// ---------------------------------------------------------------------------
extern "C" void kernel_launch(void* const* d_in, const int* in_sizes, int n_in,
                              void* d_out, int out_size, void* d_ws,
                              size_t ws_size, hipStream_t stream) {
  const float* score_act = (const float*)d_in[0];
  const float* score_bkg = (const float*)d_in[1];
  const float* feat_act = (const float*)d_in[2];
  const float* feat_bkg = (const float*)d_in[3];
  const float* label = (const float*)d_in[4];
  // d_in[5] = gt, d_in[6] = cas: unused by the reference loss
  const float* nodes = (const float*)d_in[7];
  const int* nlab = (const int*)d_in[8];
  const int* sidx = (const int*)d_in[9];
  float* out = (float*)d_out;
  float* wsf = (float*)d_ws;

  mega_kernel<<<TOT_BLOCKS, 256, 0, stream>>>(
      score_act, score_bkg, feat_act, feat_bkg, label, nodes, nlab, sidx, wsf);
  tail_kernel<<<96, 256, 0, stream>>>(wsf);
  final_kernel<<<1, 64, 0, stream>>>(wsf, out);
}